// Round 5
// baseline (115.935 us; speedup 1.0000x reference)
//
#include <hip/hip_runtime.h>
#include <math.h>

// Problem dims (fixed by setup_inputs): B=8, N=1024 -> ROWS=8192; M=2048; E=256; H1=32; H2=16
#define ROWS 8192
#define M_TOTAL 2048
#define E_DIM 256
#define H1 32
#define H2 16
#define R_PER_BLK 32   // rows per MLP block; 256 blocks
#define RBF_ROWS 4     // rows per RBF block; 2048 blocks

typedef float floatx4 __attribute__((ext_vector_type(4)));   // native vec for nontemporal builtin

__device__ __forceinline__ float gelu_exact(float x) {
    // jax.nn.gelu(approximate=False): x * 0.5 * (1 + erf(x/sqrt(2)))
    return 0.5f * x * (1.0f + erff(x * 0.70710678118654752f));
}

// 256 blocks x 256 threads; block computes sigma for 32 rows.
// w1 in LDS (b32 conflict-free reads); e-rows via global float4 broadcast loads.
__global__ __launch_bounds__(256) void sigma_mlp_v3(
    const float* __restrict__ emb,
    const float* __restrict__ w1, const float* __restrict__ b1,
    const float* __restrict__ w2, const float* __restrict__ b2,
    const float* __restrict__ w3, const float* __restrict__ b3,
    float* __restrict__ c_out)
{
    __shared__ float sw1[E_DIM * H1];        // w1[k][o] flat, 32 KB
    __shared__ float sh1[R_PER_BLK][H1 + 1];
    __shared__ float sh2[R_PER_BLK][H2 + 1];

    const int t = threadIdx.x;
    const int row0 = blockIdx.x * R_PER_BLK;

    // ---- Stage w1 (2048 float4 / 256 threads = 8 each, coalesced) ----
    {
        const float4* src_w = (const float4*)w1;
        float4* dst_w = (float4*)sw1;
        #pragma unroll
        for (int i = 0; i < 8; ++i) dst_w[t + 256 * i] = src_w[t + 256 * i];
    }
    __syncthreads();

    // ---- Layer 1: 256 -> 32. thread = (o = t&31, g = t>>5) -> rows 4g..4g+3, full K ----
    {
        const int o = t & 31;
        const int g = t >> 5;
        const int rb = g * 4;
        const float4* e0 = (const float4*)(emb + (size_t)(row0 + rb + 0) * E_DIM);
        const float4* e1 = (const float4*)(emb + (size_t)(row0 + rb + 1) * E_DIM);
        const float4* e2 = (const float4*)(emb + (size_t)(row0 + rb + 2) * E_DIM);
        const float4* e3 = (const float4*)(emb + (size_t)(row0 + rb + 3) * E_DIM);
        float acc0 = 0.f, acc1 = 0.f, acc2 = 0.f, acc3 = 0.f;
        #pragma unroll 8
        for (int k4 = 0; k4 < E_DIM / 4; ++k4) {
            // Global broadcast loads: 32 lanes share each 16B line (2 lines/instr)
            const float4 v0 = e0[k4];
            const float4 v1 = e1[k4];
            const float4 v2 = e2[k4];
            const float4 v3 = e3[k4];
            const int k = k4 * 4;
            // LDS reads: lane-stride-1 across o, upper wave-half broadcast -> conflict-free
            const float wa = sw1[(k + 0) * H1 + o];
            const float wb = sw1[(k + 1) * H1 + o];
            const float wc = sw1[(k + 2) * H1 + o];
            const float wd = sw1[(k + 3) * H1 + o];
            acc0 = fmaf(v0.x, wa, acc0); acc0 = fmaf(v0.y, wb, acc0);
            acc0 = fmaf(v0.z, wc, acc0); acc0 = fmaf(v0.w, wd, acc0);
            acc1 = fmaf(v1.x, wa, acc1); acc1 = fmaf(v1.y, wb, acc1);
            acc1 = fmaf(v1.z, wc, acc1); acc1 = fmaf(v1.w, wd, acc1);
            acc2 = fmaf(v2.x, wa, acc2); acc2 = fmaf(v2.y, wb, acc2);
            acc2 = fmaf(v2.z, wc, acc2); acc2 = fmaf(v2.w, wd, acc2);
            acc3 = fmaf(v3.x, wa, acc3); acc3 = fmaf(v3.y, wb, acc3);
            acc3 = fmaf(v3.z, wc, acc3); acc3 = fmaf(v3.w, wd, acc3);
        }
        const float bo = b1[o];
        sh1[rb + 0][o] = gelu_exact(acc0 + bo);
        sh1[rb + 1][o] = gelu_exact(acc1 + bo);
        sh1[rb + 2][o] = gelu_exact(acc2 + bo);
        sh1[rb + 3][o] = gelu_exact(acc3 + bo);
    }
    __syncthreads();

    // ---- Layer 2: 32 -> 16. thread = (o2 = t&15, rr = t>>4) -> rows rr, rr+16 ----
    {
        const int o2 = t & 15;
        const int rr = t >> 4;
        const float bo = b2[o2];
        #pragma unroll
        for (int h = 0; h < 2; ++h) {
            const int r = rr + 16 * h;
            float a = 0.f;
            #pragma unroll
            for (int k = 0; k < H1; ++k) a = fmaf(sh1[r][k], w2[k * H2 + o2], a);
            sh2[r][o2] = gelu_exact(a + bo);
        }
    }
    __syncthreads();

    // ---- Layer 3: 16 -> 1; sigmoid; c = -0.5/sigma^2 ----
    if (t < R_PER_BLK) {
        float s = 0.f;
        #pragma unroll
        for (int k = 0; k < H2; ++k) s = fmaf(sh2[t][k], w3[k], s);
        const float x = s + b3[0];
        const float sig = 1.0f / (1.0f + __expf(-x));
        const float sigma = 0.1f + 9.9f * sig;
        c_out[row0 + t] = -0.5f / (sigma * sigma);
    }
}

// 2048 blocks x 256 threads; block handles 4 rows. z float4s loaded once into
// registers and reused across rows; nontemporal float4 stores (write-once output).
__global__ __launch_bounds__(256) void rbf_v2(
    const float* __restrict__ z, const float* __restrict__ mu,
    const float* __restrict__ c_in, float* __restrict__ out)
{
    const int t = threadIdx.x;
    const int row0 = blockIdx.x * RBF_ROWS;
    const float4* zf4 = (const float4*)z;

    // This thread's 8 m-values: float4 idx t and t+256 (m = 4*idx..4*idx+3)
    const float4 za0 = zf4[2 * t + 0];
    const float4 zb0 = zf4[2 * t + 1];
    const float4 za1 = zf4[2 * (t + 256) + 0];
    const float4 zb1 = zf4[2 * (t + 256) + 1];

    const float2* mu2 = (const float2*)mu;

    #pragma unroll
    for (int r = 0; r < RBF_ROWS; ++r) {
        const int row = row0 + r;
        const float c = c_in[row];            // block-uniform -> scalar load
        const float2 muv = mu2[row];
        floatx4* o4 = (floatx4*)out + (size_t)row * (M_TOTAL / 4);
        float d0, d1;
        floatx4 v;

        d0 = za0.x - muv.x; d1 = za0.y - muv.y;
        v.x = __expf(fmaf(d1, d1, d0 * d0) * c);
        d0 = za0.z - muv.x; d1 = za0.w - muv.y;
        v.y = __expf(fmaf(d1, d1, d0 * d0) * c);
        d0 = zb0.x - muv.x; d1 = zb0.y - muv.y;
        v.z = __expf(fmaf(d1, d1, d0 * d0) * c);
        d0 = zb0.z - muv.x; d1 = zb0.w - muv.y;
        v.w = __expf(fmaf(d1, d1, d0 * d0) * c);
        __builtin_nontemporal_store(v, o4 + t);

        d0 = za1.x - muv.x; d1 = za1.y - muv.y;
        v.x = __expf(fmaf(d1, d1, d0 * d0) * c);
        d0 = za1.z - muv.x; d1 = za1.w - muv.y;
        v.y = __expf(fmaf(d1, d1, d0 * d0) * c);
        d0 = zb1.x - muv.x; d1 = zb1.y - muv.y;
        v.z = __expf(fmaf(d1, d1, d0 * d0) * c);
        d0 = zb1.z - muv.x; d1 = zb1.w - muv.y;
        v.w = __expf(fmaf(d1, d1, d0 * d0) * c);
        __builtin_nontemporal_store(v, o4 + t + 256);
    }
}

extern "C" void kernel_launch(void* const* d_in, const int* in_sizes, int n_in,
                              void* d_out, int out_size, void* d_ws, size_t ws_size,
                              hipStream_t stream) {
    const float* z   = (const float*)d_in[0];
    const float* mu  = (const float*)d_in[1];
    const float* emb = (const float*)d_in[2];
    const float* w1  = (const float*)d_in[3];
    const float* b1  = (const float*)d_in[4];
    const float* w2  = (const float*)d_in[5];
    const float* b2  = (const float*)d_in[6];
    const float* w3  = (const float*)d_in[7];
    const float* b3  = (const float*)d_in[8];
    float* out = (float*)d_out;
    float* c_ws = (float*)d_ws;   // 8192 floats = 32 KiB scratch

    sigma_mlp_v3<<<ROWS / R_PER_BLK, 256, 0, stream>>>(emb, w1, b1, w2, b2, w3, b3, c_ws);
    rbf_v2<<<ROWS / RBF_ROWS, 256, 0, stream>>>(z, mu, c_ws, out);
}

// Round 6
// 115.841 us; speedup vs baseline: 1.0008x; 1.0008x over previous
//
#include <hip/hip_runtime.h>
#include <math.h>

// Problem dims (fixed by setup_inputs): B=8, N=1024 -> ROWS=8192; M=2048; E=256; H1=32; H2=16
#define ROWS 8192
#define M_TOTAL 2048
#define E_DIM 256
#define H1 32
#define H2 16
#define R_PER_BLK 32   // rows per MLP block; 256 blocks

__device__ __forceinline__ float gelu_exact(float x) {
    // jax.nn.gelu(approximate=False): x * 0.5 * (1 + erf(x/sqrt(2)))
    return 0.5f * x * (1.0f + erff(x * 0.70710678118654752f));
}

// 256 blocks x 256 threads; block computes sigma for 32 rows.
// w1 in LDS (b32 conflict-free reads); e-rows via global float4 broadcast loads.
__global__ __launch_bounds__(256) void sigma_mlp_v3(
    const float* __restrict__ emb,
    const float* __restrict__ w1, const float* __restrict__ b1,
    const float* __restrict__ w2, const float* __restrict__ b2,
    const float* __restrict__ w3, const float* __restrict__ b3,
    float* __restrict__ c_out)
{
    __shared__ float sw1[E_DIM * H1];        // w1[k][o] flat, 32 KB
    __shared__ float sh1[R_PER_BLK][H1 + 1];
    __shared__ float sh2[R_PER_BLK][H2 + 1];

    const int t = threadIdx.x;
    const int row0 = blockIdx.x * R_PER_BLK;

    // ---- Stage w1 (2048 float4 / 256 threads = 8 each, coalesced) ----
    {
        const float4* src_w = (const float4*)w1;
        float4* dst_w = (float4*)sw1;
        #pragma unroll
        for (int i = 0; i < 8; ++i) dst_w[t + 256 * i] = src_w[t + 256 * i];
    }
    __syncthreads();

    // ---- Layer 1: 256 -> 32. thread = (o = t&31, g = t>>5) -> rows 4g..4g+3, full K ----
    {
        const int o = t & 31;
        const int g = t >> 5;
        const int rb = g * 4;
        const float4* e0 = (const float4*)(emb + (size_t)(row0 + rb + 0) * E_DIM);
        const float4* e1 = (const float4*)(emb + (size_t)(row0 + rb + 1) * E_DIM);
        const float4* e2 = (const float4*)(emb + (size_t)(row0 + rb + 2) * E_DIM);
        const float4* e3 = (const float4*)(emb + (size_t)(row0 + rb + 3) * E_DIM);
        float acc0 = 0.f, acc1 = 0.f, acc2 = 0.f, acc3 = 0.f;
        #pragma unroll 8
        for (int k4 = 0; k4 < E_DIM / 4; ++k4) {
            // Global broadcast loads: 32 lanes share each 16B line (2 lines/instr)
            const float4 v0 = e0[k4];
            const float4 v1 = e1[k4];
            const float4 v2 = e2[k4];
            const float4 v3 = e3[k4];
            const int k = k4 * 4;
            // LDS reads: lane-stride-1 across o, upper wave-half broadcast -> conflict-free
            const float wa = sw1[(k + 0) * H1 + o];
            const float wb = sw1[(k + 1) * H1 + o];
            const float wc = sw1[(k + 2) * H1 + o];
            const float wd = sw1[(k + 3) * H1 + o];
            acc0 = fmaf(v0.x, wa, acc0); acc0 = fmaf(v0.y, wb, acc0);
            acc0 = fmaf(v0.z, wc, acc0); acc0 = fmaf(v0.w, wd, acc0);
            acc1 = fmaf(v1.x, wa, acc1); acc1 = fmaf(v1.y, wb, acc1);
            acc1 = fmaf(v1.z, wc, acc1); acc1 = fmaf(v1.w, wd, acc1);
            acc2 = fmaf(v2.x, wa, acc2); acc2 = fmaf(v2.y, wb, acc2);
            acc2 = fmaf(v2.z, wc, acc2); acc2 = fmaf(v2.w, wd, acc2);
            acc3 = fmaf(v3.x, wa, acc3); acc3 = fmaf(v3.y, wb, acc3);
            acc3 = fmaf(v3.z, wc, acc3); acc3 = fmaf(v3.w, wd, acc3);
        }
        const float bo = b1[o];
        sh1[rb + 0][o] = gelu_exact(acc0 + bo);
        sh1[rb + 1][o] = gelu_exact(acc1 + bo);
        sh1[rb + 2][o] = gelu_exact(acc2 + bo);
        sh1[rb + 3][o] = gelu_exact(acc3 + bo);
    }
    __syncthreads();

    // ---- Layer 2: 32 -> 16. thread = (o2 = t&15, rr = t>>4) -> rows rr, rr+16 ----
    {
        const int o2 = t & 15;
        const int rr = t >> 4;
        const float bo = b2[o2];
        #pragma unroll
        for (int h = 0; h < 2; ++h) {
            const int r = rr + 16 * h;
            float a = 0.f;
            #pragma unroll
            for (int k = 0; k < H1; ++k) a = fmaf(sh1[r][k], w2[k * H2 + o2], a);
            sh2[r][o2] = gelu_exact(a + bo);
        }
    }
    __syncthreads();

    // ---- Layer 3: 16 -> 1; sigmoid; c = -0.5/sigma^2 ----
    if (t < R_PER_BLK) {
        float s = 0.f;
        #pragma unroll
        for (int k = 0; k < H2; ++k) s = fmaf(sh2[t][k], w3[k], s);
        const float x = s + b3[0];
        const float sig = 1.0f / (1.0f + __expf(-x));
        const float sigma = 0.1f + 9.9f * sig;
        c_out[row0 + t] = -0.5f / (sigma * sigma);
    }
}

// Grid-stride store-streaming RBF, structured like the 6.1 TB/s fill kernel:
// 2048 blocks x 256 threads x 8 iters, one plain float4 store per iter,
// device-wide sequential write stream. Stride = 524288 float4 = 1024 rows,
// so each thread's z float4s are loop-invariant (loaded once).
__global__ __launch_bounds__(256) void rbf_v4(
    const float* __restrict__ z, const float* __restrict__ mu,
    const float* __restrict__ c_in, float* __restrict__ out)
{
    const int idx0 = blockIdx.x * 256 + threadIdx.x;   // float4 index 0..524287
    const int zi = idx0 & 511;                         // float4 offset within a row
    const float4* zf4 = (const float4*)z;
    const float4 za = zf4[2 * zi + 0];                 // m = 4*zi + {0,1}
    const float4 zb = zf4[2 * zi + 1];                 // m = 4*zi + {2,3}
    const float2* mu2 = (const float2*)mu;
    float4* out4 = (float4*)out;
    const int row0 = idx0 >> 9;                        // 0..1023; wave-uniform

    #pragma unroll
    for (int i = 0; i < 8; ++i) {
        const int row = row0 + i * 1024;
        const float c = c_in[row];                     // wave-uniform, L1
        const float2 muv = mu2[row];
        float d0, d1;
        float4 v;
        d0 = za.x - muv.x; d1 = za.y - muv.y;
        v.x = __expf(fmaf(d1, d1, d0 * d0) * c);
        d0 = za.z - muv.x; d1 = za.w - muv.y;
        v.y = __expf(fmaf(d1, d1, d0 * d0) * c);
        d0 = zb.x - muv.x; d1 = zb.y - muv.y;
        v.z = __expf(fmaf(d1, d1, d0 * d0) * c);
        d0 = zb.z - muv.x; d1 = zb.w - muv.y;
        v.w = __expf(fmaf(d1, d1, d0 * d0) * c);
        out4[idx0 + i * 524288] = v;                   // sequential 16B store stream
    }
}

extern "C" void kernel_launch(void* const* d_in, const int* in_sizes, int n_in,
                              void* d_out, int out_size, void* d_ws, size_t ws_size,
                              hipStream_t stream) {
    const float* z   = (const float*)d_in[0];
    const float* mu  = (const float*)d_in[1];
    const float* emb = (const float*)d_in[2];
    const float* w1  = (const float*)d_in[3];
    const float* b1  = (const float*)d_in[4];
    const float* w2  = (const float*)d_in[5];
    const float* b2  = (const float*)d_in[6];
    const float* w3  = (const float*)d_in[7];
    const float* b3  = (const float*)d_in[8];
    float* out = (float*)d_out;
    float* c_ws = (float*)d_ws;   // 8192 floats = 32 KiB scratch

    sigma_mlp_v3<<<ROWS / R_PER_BLK, 256, 0, stream>>>(emb, w1, b1, w2, b2, w3, b3, c_ws);
    rbf_v4<<<2048, 256, 0, stream>>>(z, mu, c_ws, out);
}

// Round 7
// 112.111 us; speedup vs baseline: 1.0341x; 1.0333x over previous
//
#include <hip/hip_runtime.h>
#include <math.h>

// Problem dims (fixed by setup_inputs): B=8, N=1024 -> ROWS=8192; M=2048; E=256; H1=32; H2=16
#define ROWS 8192
#define M_TOTAL 2048
#define E_DIM 256
#define H1 32
#define H2 16

__device__ __forceinline__ float gelu_exact(float x) {
    // jax.nn.gelu(approximate=False): x * 0.5 * (1 + erf(x/sqrt(2)))
    return 0.5f * x * (1.0f + erff(x * 0.70710678118654752f));
}

// 2048 blocks x 256 threads; one wave per row (4 rows/block).
// Phase A: sigma via shuffle-only MLP (no barriers, no LDS, full occupancy).
// Phase B: RBF store stream; z transposed in LDS for conflict-free b128 reads.
__global__ __launch_bounds__(256) void fused_rbf_v2(
    const float* __restrict__ z, const float* __restrict__ mu,
    const float* __restrict__ emb,
    const float* __restrict__ w1, const float* __restrict__ b1,
    const float* __restrict__ w2, const float* __restrict__ b2,
    const float* __restrict__ w3, const float* __restrict__ b3,
    float* __restrict__ out)
{
    __shared__ float szx[M_TOTAL];   // z[.,0] transposed
    __shared__ float szy[M_TOTAL];   // z[.,1] transposed

    const int t = threadIdx.x;
    const int wave = t >> 6;
    const int l = t & 63;
    const int row = blockIdx.x * 4 + wave;

    // ---- Stage z transposed: 1024 float4 = 2048 (x,y) points ----
    {
        const float4* z4 = (const float4*)z;
        #pragma unroll
        for (int i = 0; i < 4; ++i) {
            const int p = t + 256 * i;           // float4 index -> points 2p, 2p+1
            const float4 v = z4[p];
            szx[2 * p]     = v.x; szy[2 * p]     = v.y;
            szx[2 * p + 1] = v.z; szy[2 * p + 1] = v.w;
        }
    }

    // ---- Phase A: this wave's row sigma. lane = (o = l&31, half = l>>5) ----
    const int o = l & 31;
    const int half = l >> 5;
    float acc = 0.f;
    {
        const float4* e4 = (const float4*)(emb + (size_t)row * E_DIM + half * 128);
        const float* w1p = w1 + (size_t)(half * 128) * H1 + o;
        #pragma unroll 8
        for (int k4 = 0; k4 < 32; ++k4) {
            const float4 ev = e4[k4];            // broadcast across 32 o-lanes (2 lines/instr)
            acc = fmaf(ev.x, w1p[(4 * k4 + 0) * H1], acc);
            acc = fmaf(ev.y, w1p[(4 * k4 + 1) * H1], acc);
            acc = fmaf(ev.z, w1p[(4 * k4 + 2) * H1], acc);
            acc = fmaf(ev.w, w1p[(4 * k4 + 3) * H1], acc);
        }
    }
    float h1v = acc + __shfl_xor(acc, 32);       // combine K-halves -> h1[o] in lane o (and o+32)
    h1v = gelu_exact(h1v + b1[o]);

    // Layer 2: 32 -> 16 via absolute-lane shuffles
    const int o2 = l & 15;
    float acc2 = 0.f;
    #pragma unroll
    for (int k = 0; k < H1; ++k)
        acc2 = fmaf(__shfl(h1v, k), w2[k * H2 + o2], acc2);
    const float h2v = gelu_exact(acc2 + b2[o2]);

    // Layer 3: 16 -> 1 (identical across the four 16-lane groups)
    float t3 = h2v * w3[o2];
    t3 += __shfl_xor(t3, 1);
    t3 += __shfl_xor(t3, 2);
    t3 += __shfl_xor(t3, 4);
    t3 += __shfl_xor(t3, 8);
    const float x = t3 + b3[0];
    const float sig = 1.0f / (1.0f + __expf(-x));
    const float sigma = 0.1f + 9.9f * sig;
    const float c = -0.5f / (sigma * sigma);     // every lane holds the row's coefficient

    const float2 muv = ((const float2*)mu)[row];

    __syncthreads();   // z staging complete

    // ---- Phase B: 2048 outputs for this row; 8 iters x (2 LDS b128 + float4 store) ----
    const float4* szx4 = (const float4*)szx;
    const float4* szy4 = (const float4*)szy;
    float4* o4 = (float4*)out + (size_t)row * (M_TOTAL / 4);
    #pragma unroll
    for (int i = 0; i < 8; ++i) {
        const int j = i * 64 + l;                // float4 index in row; lanes stride-1
        const float4 zx = szx4[j];               // conflict-free stride-1 b128
        const float4 zy = szy4[j];
        float4 v;
        float dx, dy;
        dx = zx.x - muv.x; dy = zy.x - muv.y;
        v.x = __expf(fmaf(dy, dy, dx * dx) * c);
        dx = zx.y - muv.x; dy = zy.y - muv.y;
        v.y = __expf(fmaf(dy, dy, dx * dx) * c);
        dx = zx.z - muv.x; dy = zy.z - muv.y;
        v.z = __expf(fmaf(dy, dy, dx * dx) * c);
        dx = zx.w - muv.x; dy = zy.w - muv.y;
        v.w = __expf(fmaf(dy, dy, dx * dx) * c);
        o4[j] = v;                               // coalesced 1KB/instr store stream
    }
}

extern "C" void kernel_launch(void* const* d_in, const int* in_sizes, int n_in,
                              void* d_out, int out_size, void* d_ws, size_t ws_size,
                              hipStream_t stream) {
    const float* z   = (const float*)d_in[0];
    const float* mu  = (const float*)d_in[1];
    const float* emb = (const float*)d_in[2];
    const float* w1  = (const float*)d_in[3];
    const float* b1  = (const float*)d_in[4];
    const float* w2  = (const float*)d_in[5];
    const float* b2  = (const float*)d_in[6];
    const float* w3  = (const float*)d_in[7];
    const float* b3  = (const float*)d_in[8];
    float* out = (float*)d_out;

    fused_rbf_v2<<<ROWS / 4, 256, 0, stream>>>(z, mu, emb, w1, b1, w2, b2, w3, b3, out);
}

// Round 8
// 105.935 us; speedup vs baseline: 1.0944x; 1.0583x over previous
//
#include <hip/hip_runtime.h>
#include <math.h>

// Problem dims (fixed by setup_inputs): B=8, N=1024 -> ROWS=8192; M=2048; E=256; H1=32; H2=16
#define ROWS 8192
#define M_TOTAL 2048
#define E_DIM 256
#define H1 32
#define H2 16
#define R_PER_BLK 16   // rows per MLP block; 512 blocks = 2/CU, 2 waves/SIMD

__device__ __forceinline__ float gelu_exact(float x) {
    // jax.nn.gelu(approximate=False): x * 0.5 * (1 + erf(x/sqrt(2)))
    return 0.5f * x * (1.0f + erff(x * 0.70710678118654752f));
}

// 512 blocks x 256 threads; block computes sigma for 16 rows.
// thread = (o = t&31, half = (t>>5)&1, g = t>>6). Each thread: 4 rows, 128 k.
// K-split doubles wave count vs v2 (2048 waves = 2/SIMD) for latency hiding;
// e + w1 both staged in LDS (global broadcast loads measured slow in r5-r7).
__global__ __launch_bounds__(256) void sigma_mlp_v6(
    const float* __restrict__ emb,
    const float* __restrict__ w1, const float* __restrict__ b1,
    const float* __restrict__ w2, const float* __restrict__ b2,
    const float* __restrict__ w3, const float* __restrict__ b3,
    float* __restrict__ c_out)
{
    __shared__ float sw1[E_DIM * H1];          // w1[k][o] flat, 32 KB
    __shared__ float se[R_PER_BLK * E_DIM];    // 16 rows x 256, 16 KB
    __shared__ float sh1[R_PER_BLK][H1 + 1];
    __shared__ float sh2[R_PER_BLK][H2 + 1];

    const int t = threadIdx.x;
    const int row0 = blockIdx.x * R_PER_BLK;

    // ---- Stage w1 (2048 float4) + e (1024 float4), coalesced ----
    {
        const float4* src_w = (const float4*)w1;
        float4* dst_w = (float4*)sw1;
        #pragma unroll
        for (int i = 0; i < 8; ++i) dst_w[t + 256 * i] = src_w[t + 256 * i];
        const float4* src_e = (const float4*)(emb + (size_t)row0 * E_DIM);
        float4* dst_e = (float4*)se;
        #pragma unroll
        for (int i = 0; i < 4; ++i) dst_e[t + 256 * i] = src_e[t + 256 * i];
    }
    __syncthreads();

    // ---- Layer 1: 256 -> 32, K split across wave halves ----
    {
        const int o = t & 31;
        const int half = (t >> 5) & 1;
        const int g = t >> 6;                  // wave id 0..3
        const int rb = g * 4;                  // this wave's 4 rows
        const int kbase = half * (E_DIM / 2);  // 0 or 128
        const float4* se4 = (const float4*)se;
        float acc0 = 0.f, acc1 = 0.f, acc2 = 0.f, acc3 = 0.f;
        #pragma unroll 8
        for (int k4 = 0; k4 < 32; ++k4) {      // 32 iters x 4 k = 128 k per half
            const int k = kbase + k4 * 4;
            // e reads: per-instr 2 addresses (one per half) x broadcast over o -> free
            const float4 e0 = se4[(rb + 0) * (E_DIM / 4) + (k >> 2)];
            const float4 e1 = se4[(rb + 1) * (E_DIM / 4) + (k >> 2)];
            const float4 e2 = se4[(rb + 2) * (E_DIM / 4) + (k >> 2)];
            const float4 e3 = se4[(rb + 3) * (E_DIM / 4) + (k >> 2)];
            // w1 reads: stride-1 over o, 2 k-addresses per instr -> conflict-free
            const float wa = sw1[(k + 0) * H1 + o];
            const float wb = sw1[(k + 1) * H1 + o];
            const float wc = sw1[(k + 2) * H1 + o];
            const float wd = sw1[(k + 3) * H1 + o];
            acc0 = fmaf(e0.x, wa, acc0); acc0 = fmaf(e0.y, wb, acc0);
            acc0 = fmaf(e0.z, wc, acc0); acc0 = fmaf(e0.w, wd, acc0);
            acc1 = fmaf(e1.x, wa, acc1); acc1 = fmaf(e1.y, wb, acc1);
            acc1 = fmaf(e1.z, wc, acc1); acc1 = fmaf(e1.w, wd, acc1);
            acc2 = fmaf(e2.x, wa, acc2); acc2 = fmaf(e2.y, wb, acc2);
            acc2 = fmaf(e2.z, wc, acc2); acc2 = fmaf(e2.w, wd, acc2);
            acc3 = fmaf(e3.x, wa, acc3); acc3 = fmaf(e3.y, wb, acc3);
            acc3 = fmaf(e3.z, wc, acc3); acc3 = fmaf(e3.w, wd, acc3);
        }
        // Combine K-halves: lanes o and o+32 hold the two halves
        acc0 += __shfl_xor(acc0, 32);
        acc1 += __shfl_xor(acc1, 32);
        acc2 += __shfl_xor(acc2, 32);
        acc3 += __shfl_xor(acc3, 32);
        const float bo = b1[o];
        if (half == 0) {
            sh1[rb + 0][o] = gelu_exact(acc0 + bo);
            sh1[rb + 1][o] = gelu_exact(acc1 + bo);
            sh1[rb + 2][o] = gelu_exact(acc2 + bo);
            sh1[rb + 3][o] = gelu_exact(acc3 + bo);
        }
    }
    __syncthreads();

    // ---- Layer 2: 32 -> 16. 256 threads = 16 rows x 16 outputs exactly ----
    {
        const int o2 = t & 15;
        const int r = t >> 4;                  // 0..15
        float a = 0.f;
        #pragma unroll
        for (int k = 0; k < H1; ++k) a = fmaf(sh1[r][k], w2[k * H2 + o2], a);
        sh2[r][o2] = gelu_exact(a + b2[o2]);
    }
    __syncthreads();

    // ---- Layer 3: 16 -> 1; sigmoid; c = -0.5/sigma^2 ----
    if (t < R_PER_BLK) {
        float s = 0.f;
        #pragma unroll
        for (int k = 0; k < H2; ++k) s = fmaf(sh2[t][k], w3[k], s);
        const float x = s + b3[0];
        const float sig = 1.0f / (1.0f + __expf(-x));
        const float sigma = 0.1f + 9.9f * sig;
        c_out[row0 + t] = -0.5f / (sigma * sigma);
    }
}

// One block per (b,n) row; 256 threads x 8 m-values each; float4 loads/stores.
// (Round-3 structure — measured at ~12 us / near store-limit.)
__global__ __launch_bounds__(256) void rbf_kernel(
    const float* __restrict__ z, const float* __restrict__ mu,
    const float* __restrict__ c_in, float* __restrict__ out)
{
    const int row = blockIdx.x;
    const int t = threadIdx.x;
    const float c = c_in[row];                 // wave-uniform
    const float mu0 = mu[row * 2 + 0];
    const float mu1 = mu[row * 2 + 1];
    const float4* zf4 = (const float4*)z;      // z[M][2]: float4 j = (z[2j][.], z[2j+1][.])
    float4* out4 = (float4*)out + (size_t)row * (M_TOTAL / 4);

    #pragma unroll
    for (int i = 0; i < 2; ++i) {
        const int idx = i * 256 + t;           // float4 index within the row: 0..511
        const float4 za = zf4[idx * 2 + 0];    // m = 4*idx + {0,1}
        const float4 zb = zf4[idx * 2 + 1];    // m = 4*idx + {2,3}
        float4 r;
        float d0, d1;
        d0 = za.x - mu0; d1 = za.y - mu1;
        r.x = __expf(fmaf(d1, d1, d0 * d0) * c);
        d0 = za.z - mu0; d1 = za.w - mu1;
        r.y = __expf(fmaf(d1, d1, d0 * d0) * c);
        d0 = zb.x - mu0; d1 = zb.y - mu1;
        r.z = __expf(fmaf(d1, d1, d0 * d0) * c);
        d0 = zb.z - mu0; d1 = zb.w - mu1;
        r.w = __expf(fmaf(d1, d1, d0 * d0) * c);
        out4[idx] = r;                         // coalesced 16B stores
    }
}

extern "C" void kernel_launch(void* const* d_in, const int* in_sizes, int n_in,
                              void* d_out, int out_size, void* d_ws, size_t ws_size,
                              hipStream_t stream) {
    const float* z   = (const float*)d_in[0];
    const float* mu  = (const float*)d_in[1];
    const float* emb = (const float*)d_in[2];
    const float* w1  = (const float*)d_in[3];
    const float* b1  = (const float*)d_in[4];
    const float* w2  = (const float*)d_in[5];
    const float* b2  = (const float*)d_in[6];
    const float* w3  = (const float*)d_in[7];
    const float* b3  = (const float*)d_in[8];
    float* out = (float*)d_out;
    float* c_ws = (float*)d_ws;   // 8192 floats = 32 KiB scratch

    sigma_mlp_v6<<<ROWS / R_PER_BLK, 256, 0, stream>>>(emb, w1, b1, w2, b2, w3, b3, c_ws);
    rbf_kernel<<<ROWS, 256, 0, stream>>>(z, mu, c_ws, out);
}